// Round 10
// baseline (63.012 us; speedup 1.0000x reference)
//
#include <hip/hip_runtime.h>
#include <hip/hip_bf16.h>

typedef __attribute__((ext_vector_type(8))) short short8;
typedef __attribute__((ext_vector_type(4))) float f32x4;
typedef __attribute__((address_space(1))) const unsigned int glb_u32;
typedef __attribute__((address_space(3))) unsigned int lds_u32;

#define DIMD 128
#define NSPLIT 32            // 256-col splits; also the partial[] stride
#define WR 64                // rows per wave
#define ROWS_PER_BLOCK 256   // 4 waves * WR
#define CPS 256              // cols per block (= one split), staged once

// scale = sqrt(2 * log2(e)) so that acc = (c*zn_i)·(c*zn_j) = 2*log2(e)*cos
// -> exp2(acc) = e^(cos/T) directly, and logit s = acc * ln2.
#define ZSCALE 1.69864363f
#define LN2 0.6931471805599453f

// ---------------- Kernel 1: normalize rows of [z_i; z_j] -> scaled bf16 ------
__global__ __launch_bounds__(256) void nrm_kernel(const float* __restrict__ zi,
                                                  const float* __restrict__ zj,
                                                  __hip_bfloat16* __restrict__ zn,
                                                  float* __restrict__ out, int B) {
  if (blockIdx.x == 0 && threadIdx.x == 0) out[0] = 0.0f;
  int wave = threadIdx.x >> 6, lane = threadIdx.x & 63;
  int N = 2 * B;
  int row = blockIdx.x * 4 + wave;
  if (row >= N) return;
  const float* src = (row < B) ? (zi + (size_t)row * DIMD)
                               : (zj + (size_t)(row - B) * DIMD);
  float2 v = *(const float2*)(src + lane * 2);
  float ss = v.x * v.x + v.y * v.y;
  #pragma unroll
  for (int off = 32; off; off >>= 1) ss += __shfl_xor(ss, off);
  float nrm = sqrtf(ss);
  float r = ZSCALE / fmaxf(nrm, 1e-8f);
  __hip_bfloat16* dst = zn + (size_t)row * DIMD + lane * 2;
  dst[0] = __float2bfloat16(v.x * r);
  dst[1] = __float2bfloat16(v.y * r);
}

// ---------------- Kernel 2: fused zn*zn^T -> sum-of-exp partials, UPPER-TRI --
// exp(sim) is symmetric: only blocks (r,c) with c>=r are computed (528 of
// 1024 tiles of 256x256). Off-diagonal blocks produce BOTH the row-sums for
// their row-stripe (partial[i][c]) and, via the mirror, the row-sums of
// their col-stripe restricted to their row-split (partial[j][r], from
// column sums). Every partial[i][k] has exactly one writer -> plain stores.
// Positive pairs (i, i±B) live only in blocks with c == r+16; both pos[i]
// and pos[i+B] are written there. Blocks: 4 waves x 64 rows, B panel staged
// once in 64 KB LDS via global_load_lds (pre-swizzled source, G21), one
// barrier. Flat-only launch_bounds: every min-waves cap spilled (R4/6/8).
__global__ __launch_bounds__(256) void sim_kernel(const __hip_bfloat16* __restrict__ znb,
                                                  float* __restrict__ partial,
                                                  float* __restrict__ pos, int B) {
  const ushort* zn = (const ushort*)znb;
  const int N = 2 * B;
  const int tid = threadIdx.x;
  const int wave = tid >> 6, lane = tid & 63;
  const int l15 = lane & 15, lh = lane >> 4;

  // decode upper-triangle block (r, c), 0 <= r <= c < NSPLIT
  int rem = blockIdx.x, r = 0;
  while (rem >= (NSPLIT - r)) { rem -= (NSPLIT - r); ++r; }
  const int c = r + rem;

  const int Rr = r * CPS + wave * WR;  // this wave's 64 rows
  const int Cc = c * CPS;              // block's 256 cols

  __shared__ ushort lds[CPS * DIMD];   // 64 KB B panel
  __shared__ float colred[4][CPS];     // 4 KB cross-wave col-sum reduce

  // ---- stage B panel: 16 global_load_lds calls, 16B/lane ----
  // call c_: col = c_*16 + wave*4 + (lane>>4), slot (lane&15). Linear LDS
  // dest; global source pre-swizzled so slot kb' holds k-chunk kb'^(col&7)
  // (c_*16 ≡ 0 mod 8 keeps the per-lane swizzle invariant across calls).
  {
    const int myCol = wave * 4 + lh;
    const int myKb = l15 ^ (myCol & 7);
    const ushort* gsrc0 = zn + (size_t)(Cc + myCol) * DIMD + myKb * 8;
    #pragma unroll
    for (int c_ = 0; c_ < 16; ++c_)
      __builtin_amdgcn_global_load_lds(
          (glb_u32*)(gsrc0 + (size_t)c_ * 16 * DIMD),
          (lds_u32*)&lds[(c_ * 16 + wave * 4) * DIMD], 16, 0, 0);
  }

  // ---- A fragments (in flight with B staging) ----
  // lane l, elems j: A[row = l&15][k = kc*32 + 8*(l>>4) + j]
  short8 a[4][4];
  #pragma unroll
  for (int rg = 0; rg < 4; ++rg) {
    const ushort* ar = zn + (size_t)(Rr + rg * 16 + l15) * DIMD + lh * 8;
    #pragma unroll
    for (int kc = 0; kc < 4; ++kc) a[rg][kc] = *(const short8*)(ar + kc * 32);
  }

  float rs[4][4];
  #pragma unroll
  for (int rg = 0; rg < 4; ++rg)
    #pragma unroll
    for (int rr = 0; rr < 4; ++rr) rs[rg][rr] = 0.0f;

  // swizzled read offsets: (sub*16+l15)&7 == l15&7, constant over sub
  int roff[4];
  #pragma unroll
  for (int kc = 0; kc < 4; ++kc) roff[kc] = ((kc * 4 + lh) ^ (l15 & 7)) * 8;

  __syncthreads();  // drains staging + A loads

  if (r == c) {
    // ---- diagonal block: full symmetric tile, mask j==i, row-sums only ----
    #pragma unroll 4
    for (int sub = 0; sub < CPS / 16; ++sub) {
      const ushort* lp = &lds[(sub * 16 + l15) * DIMD];
      short8 bb[4];
      #pragma unroll
      for (int kc = 0; kc < 4; ++kc) bb[kc] = *(const short8*)(lp + roff[kc]);
      #pragma unroll
      for (int rg = 0; rg < 4; ++rg) {
        f32x4 acc = {0.f, 0.f, 0.f, 0.f};
        acc = __builtin_amdgcn_mfma_f32_16x16x32_bf16(a[rg][0], bb[0], acc, 0, 0, 0);
        acc = __builtin_amdgcn_mfma_f32_16x16x32_bf16(a[rg][1], bb[1], acc, 0, 0, 0);
        acc = __builtin_amdgcn_mfma_f32_16x16x32_bf16(a[rg][2], bb[2], acc, 0, 0, 0);
        acc = __builtin_amdgcn_mfma_f32_16x16x32_bf16(a[rg][3], bb[3], acc, 0, 0, 0);
        #pragma unroll
        for (int rr = 0; rr < 4; ++rr) {
          int i_ = Rr + rg * 16 + lh * 4 + rr;   // C/D: row=(lane>>4)*4+reg
          int jg_ = Cc + sub * 16 + l15;         //       col=lane&15
          if (jg_ != i_) rs[rg][rr] += __builtin_amdgcn_exp2f(acc[rr]);
        }
      }
    }
  } else {
    // ---- off-diagonal: row-sums + mirror col-sums (+ rare pos pairs) ----
    #pragma unroll 4
    for (int sub = 0; sub < CPS / 16; ++sub) {
      const ushort* lp = &lds[(sub * 16 + l15) * DIMD];
      short8 bb[4];
      #pragma unroll
      for (int kc = 0; kc < 4; ++kc) bb[kc] = *(const short8*)(lp + roff[kc]);
      float ce = 0.0f;
      #pragma unroll
      for (int rg = 0; rg < 4; ++rg) {
        f32x4 acc = {0.f, 0.f, 0.f, 0.f};
        acc = __builtin_amdgcn_mfma_f32_16x16x32_bf16(a[rg][0], bb[0], acc, 0, 0, 0);
        acc = __builtin_amdgcn_mfma_f32_16x16x32_bf16(a[rg][1], bb[1], acc, 0, 0, 0);
        acc = __builtin_amdgcn_mfma_f32_16x16x32_bf16(a[rg][2], bb[2], acc, 0, 0, 0);
        acc = __builtin_amdgcn_mfma_f32_16x16x32_bf16(a[rg][3], bb[3], acc, 0, 0, 0);
        #pragma unroll
        for (int rr = 0; rr < 4; ++rr) {
          int i_ = Rr + rg * 16 + lh * 4 + rr;
          int jg_ = Cc + sub * 16 + l15;
          float e = __builtin_amdgcn_exp2f(acc[rr]);
          rs[rg][rr] += e;
          ce += e;
          if (jg_ == ((i_ + B) & (N - 1))) {   // only fires when c == r+16
            float s = acc[rr] * LN2;
            pos[i_] = s;
            pos[jg_] = s;                      // mirror positive
          }
        }
      }
      // reduce this sub's col-sums over the 4 row-groups' lanes (lh axis)
      ce += __shfl_xor(ce, 16);
      ce += __shfl_xor(ce, 32);
      if (lh == 0) colred[wave][sub * 16 + l15] = ce;
    }
  }

  // row-sum: reduce across the 16 lanes sharing (lane>>4), then store
  #pragma unroll
  for (int rg = 0; rg < 4; ++rg) {
    #pragma unroll
    for (int rr = 0; rr < 4; ++rr) {
      #pragma unroll
      for (int off = 1; off < 16; off <<= 1)
        rs[rg][rr] += __shfl_xor(rs[rg][rr], off);
    }
  }
  if (l15 == 0) {
    #pragma unroll
    for (int rg = 0; rg < 4; ++rg)
      #pragma unroll
      for (int rr = 0; rr < 4; ++rr)
        partial[(size_t)(Rr + rg * 16 + lh * 4 + rr) * NSPLIT + c] = rs[rg][rr];
  }

  if (r != c) {
    // combine the 4 waves' col-sums -> mirror row-sums partial[j][r]
    __syncthreads();
    float cs = colred[0][tid] + colred[1][tid] + colred[2][tid] + colred[3][tid];
    partial[(size_t)(Cc + tid) * NSPLIT + r] = cs;
  }
}

// ---------------- Kernel 3: row_loss = log(sum) - pos; mean over rows -------
__global__ __launch_bounds__(256) void fin_kernel(const float* __restrict__ partial,
                                                  const float* __restrict__ pos,
                                                  float* __restrict__ out, int N) {
  int i = blockIdx.x * 256 + threadIdx.x;
  float li = 0.0f;
  if (i < N) {
    float s = 0.0f;
    #pragma unroll
    for (int q = 0; q < NSPLIT; ++q) s += partial[(size_t)i * NSPLIT + q];
    li = __builtin_amdgcn_logf(s) * LN2 - pos[i];
  }
  #pragma unroll
  for (int off = 32; off; off >>= 1) li += __shfl_xor(li, off);
  __shared__ float red[4];
  int wave = threadIdx.x >> 6, lane = threadIdx.x & 63;
  if (lane == 0) red[wave] = li;
  __syncthreads();
  if (threadIdx.x == 0) {
    float bs = red[0] + red[1] + red[2] + red[3];
    atomicAdd(out, bs / (float)N);
  }
}

extern "C" void kernel_launch(void* const* d_in, const int* in_sizes, int n_in,
                              void* d_out, int out_size, void* d_ws, size_t ws_size,
                              hipStream_t stream) {
  const float* zi = (const float*)d_in[0];
  const float* zj = (const float*)d_in[1];
  const int B = in_sizes[0] / DIMD;   // 4096
  const int N = 2 * B;                // 8192
  float* out = (float*)d_out;

  char* ws = (char*)d_ws;
  __hip_bfloat16* zn = (__hip_bfloat16*)ws;                       // N*D*2 bytes
  float* partial = (float*)(ws + (size_t)N * DIMD * 2);           // N*NSPLIT*4
  float* pos = (float*)(ws + (size_t)N * DIMD * 2 + (size_t)N * NSPLIT * 4);

  nrm_kernel<<<N / 4, 256, 0, stream>>>(zi, zj, zn, out, B);
  const int ntri = NSPLIT * (NSPLIT + 1) / 2;   // 528 upper-tri blocks
  sim_kernel<<<ntri, 256, 0, stream>>>(zn, partial, pos, B);
  fin_kernel<<<N / 256, 256, 0, stream>>>(partial, pos, out, N);
}

// Round 12
// 43.195 us; speedup vs baseline: 1.4588x; 1.4588x over previous
//
#include <hip/hip_runtime.h>
#include <hip/hip_bf16.h>

typedef __attribute__((ext_vector_type(8))) short short8;
typedef __attribute__((ext_vector_type(4))) float f32x4;
typedef __attribute__((address_space(1))) const unsigned int glb_u32;
typedef __attribute__((address_space(3))) unsigned int lds_u32;

#define DIMD 128
#define S 128                // square stripe size (rows and cols per tile)
#define NS 64                // number of stripes = 8192 / S
#define WRW 32               // rows per wave (4 waves x 32 = 128-row stripe)

// scale = sqrt(2 * log2(e)) so that acc = (c*zn_i)·(c*zn_j) = 2*log2(e)*cos
// -> exp2(acc) = e^(cos/T) directly, and logit s = acc * ln2.
#define ZSCALE 1.69864363f
#define LN2 0.6931471805599453f

// ---------------- Kernel 1: normalize rows -> scaled bf16; zero accumulators -
__global__ __launch_bounds__(256) void nrm_kernel(const float* __restrict__ zi,
                                                  const float* __restrict__ zj,
                                                  __hip_bfloat16* __restrict__ zn,
                                                  float* __restrict__ out,
                                                  float* __restrict__ rowsum, int B) {
  if (blockIdx.x == 0 && threadIdx.x == 0) out[0] = 0.0f;
  int wave = threadIdx.x >> 6, lane = threadIdx.x & 63;
  int N = 2 * B;
  int row = blockIdx.x * 4 + wave;
  if (row >= N) return;
  if (lane == 0) rowsum[row] = 0.0f;   // fresh accumulator every launch
  const float* src = (row < B) ? (zi + (size_t)row * DIMD)
                               : (zj + (size_t)(row - B) * DIMD);
  float2 v = *(const float2*)(src + lane * 2);
  float ss = v.x * v.x + v.y * v.y;
  #pragma unroll
  for (int off = 32; off; off >>= 1) ss += __shfl_xor(ss, off);
  float nrm = sqrtf(ss);
  float r = ZSCALE / fmaxf(nrm, 1e-8f);
  __hip_bfloat16* dst = zn + (size_t)row * DIMD + lane * 2;
  dst[0] = __float2bfloat16(v.x * r);
  dst[1] = __float2bfloat16(v.y * r);
}

// ---------------- Kernel 2: fused zn*zn^T -> sum-of-exp, UPPER-TRIANGLE -----
// exp(sim) symmetric: only tiles (r,c), c>=r, of 128x128 computed (2080 of
// 4096). Off-diag tiles contribute row-sums for their rows AND (mirror)
// col-sums for their cols; both go into rowsum[] via atomicAdd (64 adds per
// row per launch — negligible contention; fp reorder jitter ~1e-6 << 0.18
// threshold). Positive pairs live only in tiles c == r+32; both pos[i] and
// pos[i+B] are written there (plain stores, unique writer).
// WS footprint deliberately small (R11 lesson: partial[N][64] pushed ws past
// 4 MiB -> page fault -> queue hang): zn 2MB + pos 32KB + rowsum 32KB.
// Flat-only launch_bounds (min-waves caps spilled in R4/6/8).
__global__ __launch_bounds__(256) void sim_kernel(const __hip_bfloat16* __restrict__ znb,
                                                  float* __restrict__ rowsum,
                                                  float* __restrict__ pos, int B) {
  const ushort* zn = (const ushort*)znb;
  const int N = 2 * B;
  const int tid = threadIdx.x;
  const int wave = tid >> 6, lane = tid & 63;
  const int l15 = lane & 15, lh = lane >> 4;

  // decode upper-triangle tile (r, c), 0 <= r <= c < NS
  int rem = blockIdx.x, r = 0;
  while (rem >= (NS - r)) { rem -= (NS - r); ++r; }
  const int c = r + rem;

  const int Rr = r * S + wave * WRW;   // this wave's 32 rows
  const int Cc = c * S;                // tile's 128 cols

  __shared__ ushort lds[S * DIMD];     // 32 KB B panel
  __shared__ float colred[4][S];       // 2 KB cross-wave col-sum reduce

  // ---- stage B panel: 8 global_load_lds calls, 16B/lane ----
  // call c_: col = c_*16 + wave*4 + (lane>>4), slot (lane&15). Linear LDS
  // dest; source pre-swizzled so slot kb' holds k-chunk kb'^(col&7)
  // (c_*16 ≡ 0 mod 8 keeps the per-lane swizzle invariant across calls).
  {
    const int myCol = wave * 4 + lh;
    const int myKb = l15 ^ (myCol & 7);
    const ushort* gsrc0 = zn + (size_t)(Cc + myCol) * DIMD + myKb * 8;
    #pragma unroll
    for (int c_ = 0; c_ < 8; ++c_)
      __builtin_amdgcn_global_load_lds(
          (glb_u32*)(gsrc0 + (size_t)c_ * 16 * DIMD),
          (lds_u32*)&lds[(c_ * 16 + wave * 4) * DIMD], 16, 0, 0);
  }

  // ---- A fragments (in flight with B staging): 2 row-groups x 4 k-chunks --
  // lane l, elems j: A[row = l&15][k = kc*32 + 8*(l>>4) + j]
  short8 a[2][4];
  #pragma unroll
  for (int rg = 0; rg < 2; ++rg) {
    const ushort* ar = zn + (size_t)(Rr + rg * 16 + l15) * DIMD + lh * 8;
    #pragma unroll
    for (int kc = 0; kc < 4; ++kc) a[rg][kc] = *(const short8*)(ar + kc * 32);
  }

  float rs[2][4];
  #pragma unroll
  for (int rg = 0; rg < 2; ++rg)
    #pragma unroll
    for (int rr = 0; rr < 4; ++rr) rs[rg][rr] = 0.0f;

  // swizzled read offsets: (sub*16+l15)&7 == l15&7, constant over sub
  int roff[4];
  #pragma unroll
  for (int kc = 0; kc < 4; ++kc) roff[kc] = ((kc * 4 + lh) ^ (l15 & 7)) * 8;

  __syncthreads();  // drains staging + A loads

  if (r == c) {
    // ---- diagonal tile: mask j==i, row-sums only ----
    #pragma unroll 4
    for (int sub = 0; sub < S / 16; ++sub) {
      const ushort* lp = &lds[(sub * 16 + l15) * DIMD];
      short8 bb[4];
      #pragma unroll
      for (int kc = 0; kc < 4; ++kc) bb[kc] = *(const short8*)(lp + roff[kc]);
      #pragma unroll
      for (int rg = 0; rg < 2; ++rg) {
        f32x4 acc = {0.f, 0.f, 0.f, 0.f};
        acc = __builtin_amdgcn_mfma_f32_16x16x32_bf16(a[rg][0], bb[0], acc, 0, 0, 0);
        acc = __builtin_amdgcn_mfma_f32_16x16x32_bf16(a[rg][1], bb[1], acc, 0, 0, 0);
        acc = __builtin_amdgcn_mfma_f32_16x16x32_bf16(a[rg][2], bb[2], acc, 0, 0, 0);
        acc = __builtin_amdgcn_mfma_f32_16x16x32_bf16(a[rg][3], bb[3], acc, 0, 0, 0);
        #pragma unroll
        for (int rr = 0; rr < 4; ++rr) {
          int i_ = Rr + rg * 16 + lh * 4 + rr;   // C/D: row=(lane>>4)*4+reg
          int jg_ = Cc + sub * 16 + l15;         //       col=lane&15
          if (jg_ != i_) rs[rg][rr] += __builtin_amdgcn_exp2f(acc[rr]);
        }
      }
    }
  } else {
    // ---- off-diagonal: row-sums + mirror col-sums (+ rare pos pairs) ----
    #pragma unroll 4
    for (int sub = 0; sub < S / 16; ++sub) {
      const ushort* lp = &lds[(sub * 16 + l15) * DIMD];
      short8 bb[4];
      #pragma unroll
      for (int kc = 0; kc < 4; ++kc) bb[kc] = *(const short8*)(lp + roff[kc]);
      float ce = 0.0f;
      #pragma unroll
      for (int rg = 0; rg < 2; ++rg) {
        f32x4 acc = {0.f, 0.f, 0.f, 0.f};
        acc = __builtin_amdgcn_mfma_f32_16x16x32_bf16(a[rg][0], bb[0], acc, 0, 0, 0);
        acc = __builtin_amdgcn_mfma_f32_16x16x32_bf16(a[rg][1], bb[1], acc, 0, 0, 0);
        acc = __builtin_amdgcn_mfma_f32_16x16x32_bf16(a[rg][2], bb[2], acc, 0, 0, 0);
        acc = __builtin_amdgcn_mfma_f32_16x16x32_bf16(a[rg][3], bb[3], acc, 0, 0, 0);
        #pragma unroll
        for (int rr = 0; rr < 4; ++rr) {
          int i_ = Rr + rg * 16 + lh * 4 + rr;
          int jg_ = Cc + sub * 16 + l15;
          float e = __builtin_amdgcn_exp2f(acc[rr]);
          rs[rg][rr] += e;
          ce += e;
          if (jg_ == ((i_ + B) & (N - 1))) {   // only fires when c == r+32
            float s_ = acc[rr] * LN2;
            pos[i_] = s_;
            pos[jg_] = s_;                     // mirror positive
          }
        }
      }
      // this sub's per-col sums: reduce over the lh axis (4 row-quarters)
      ce += __shfl_xor(ce, 16);
      ce += __shfl_xor(ce, 32);
      if (lh == 0) colred[wave][sub * 16 + l15] = ce;
    }
  }

  // row-sum: reduce across the 16 lanes sharing (lane>>4), then accumulate
  #pragma unroll
  for (int rg = 0; rg < 2; ++rg) {
    #pragma unroll
    for (int rr = 0; rr < 4; ++rr) {
      #pragma unroll
      for (int off = 1; off < 16; off <<= 1)
        rs[rg][rr] += __shfl_xor(rs[rg][rr], off);
    }
  }
  if (l15 == 0) {
    #pragma unroll
    for (int rg = 0; rg < 2; ++rg)
      #pragma unroll
      for (int rr = 0; rr < 4; ++rr)
        atomicAdd(&rowsum[Rr + rg * 16 + lh * 4 + rr], rs[rg][rr]);
  }

  if (r != c) {
    // combine the 4 waves' col-sums -> mirror contribution to rowsum[j]
    __syncthreads();
    if (tid < S) {
      float cs = colred[0][tid] + colred[1][tid] + colred[2][tid] + colred[3][tid];
      atomicAdd(&rowsum[Cc + tid], cs);
    }
  }
}

// ---------------- Kernel 3: row_loss = log(sum) - pos; mean over rows -------
__global__ __launch_bounds__(256) void fin_kernel(const float* __restrict__ rowsum,
                                                  const float* __restrict__ pos,
                                                  float* __restrict__ out, int N) {
  int i = blockIdx.x * 256 + threadIdx.x;
  float li = 0.0f;
  if (i < N)
    li = __builtin_amdgcn_logf(rowsum[i]) * LN2 - pos[i];
  #pragma unroll
  for (int off = 32; off; off >>= 1) li += __shfl_xor(li, off);
  __shared__ float red[4];
  int wave = threadIdx.x >> 6, lane = threadIdx.x & 63;
  if (lane == 0) red[wave] = li;
  __syncthreads();
  if (threadIdx.x == 0) {
    float bs = red[0] + red[1] + red[2] + red[3];
    atomicAdd(out, bs / (float)N);
  }
}

extern "C" void kernel_launch(void* const* d_in, const int* in_sizes, int n_in,
                              void* d_out, int out_size, void* d_ws, size_t ws_size,
                              hipStream_t stream) {
  const float* zi = (const float*)d_in[0];
  const float* zj = (const float*)d_in[1];
  const int B = in_sizes[0] / DIMD;   // 4096
  const int N = 2 * B;                // 8192
  float* out = (float*)d_out;

  char* ws = (char*)d_ws;
  __hip_bfloat16* zn = (__hip_bfloat16*)ws;                  // N*D*2 = 2 MB
  float* pos = (float*)(ws + (size_t)N * DIMD * 2);          // N*4 = 32 KB
  float* rowsum = (float*)(ws + (size_t)N * DIMD * 2 + (size_t)N * 4);  // 32 KB

  nrm_kernel<<<N / 4, 256, 0, stream>>>(zi, zj, zn, out, rowsum, B);
  const int ntri = NS * (NS + 1) / 2;   // 2080 upper-tri tiles
  sim_kernel<<<ntri, 256, 0, stream>>>(zn, rowsum, pos, B);
  fin_kernel<<<N / 256, 256, 0, stream>>>(rowsum, pos, out, N);
}

// Round 13
// 38.583 us; speedup vs baseline: 1.6331x; 1.1195x over previous
//
#include <hip/hip_runtime.h>
#include <hip/hip_bf16.h>

typedef __attribute__((ext_vector_type(8))) short short8;
typedef __attribute__((ext_vector_type(4))) float f32x4;
typedef __attribute__((address_space(1))) const unsigned int glb_u32;
typedef __attribute__((address_space(3))) unsigned int lds_u32;

#define DIMD 128
#define S 128                // square tile size
#define NS 64                // stripes = 8192 / S
#define NPB 32               // B/S: pos pairs live in tiles c == r + NPB
#define WRW 32               // rows per wave (4 waves x 32 = 128-row stripe)

// scale = sqrt(2 * log2(e)) so acc = 2*log2(e)*cos -> exp2(acc) = e^(cos/T);
// logit s = acc * ln2.
#define ZSCALE 1.69864363f
#define LN2 0.6931471805599453f

// ---------------- Kernel 1: normalize rows -> scaled bf16; zero accumulators -
__global__ __launch_bounds__(256) void nrm_kernel(const float* __restrict__ zi,
                                                  const float* __restrict__ zj,
                                                  __hip_bfloat16* __restrict__ zn,
                                                  float* __restrict__ out,
                                                  float* __restrict__ rowsum, int B) {
  if (blockIdx.x == 0 && threadIdx.x == 0) out[0] = 0.0f;
  int wave = threadIdx.x >> 6, lane = threadIdx.x & 63;
  int N = 2 * B;
  int row = blockIdx.x * 4 + wave;
  if (row >= N) return;
  if (lane == 0) rowsum[row] = 0.0f;
  const float* src = (row < B) ? (zi + (size_t)row * DIMD)
                               : (zj + (size_t)(row - B) * DIMD);
  float2 v = *(const float2*)(src + lane * 2);
  float ss = v.x * v.x + v.y * v.y;
  #pragma unroll
  for (int off = 32; off; off >>= 1) ss += __shfl_xor(ss, off);
  float nrm = sqrtf(ss);
  float r = ZSCALE / fmaxf(nrm, 1e-8f);
  __hip_bfloat16* dst = zn + (size_t)row * DIMD + lane * 2;
  dst[0] = __float2bfloat16(v.x * r);
  dst[1] = __float2bfloat16(v.y * r);
}

// ---------------- Kernel 2: zn*zn^T upper-triangle, sum-of-exp --------------
// 2080 tiles of 128x128 (c>=r). Off-diag tiles add row-sums AND mirror
// col-sums to rowsum[] (atomicAdd; 64 adds/row/launch). Positives only in
// tiles c==r+NPB (local diagonal); diag tiles (r==c) mask j==i. The plain
// path (1984 tiles) is a branch-free hand-pipelined 2-sub loop: 4 live MFMA
// chains, next pair's ds_reads issued between MFMA and exp epilogue.

#define LDB(BB, SUB)                                                          \
  {                                                                           \
    const ushort* lp_ = &lds[((SUB) * 16 + l15) * DIMD];                      \
    _Pragma("unroll")                                                         \
    for (int kc = 0; kc < 4; ++kc) BB[kc] = *(const short8*)(lp_ + roff[kc]); \
  }

#define MM4(ACC, RG, BB)                                                      \
  ACC = __builtin_amdgcn_mfma_f32_16x16x32_bf16(a[RG][0], BB[0], ACC, 0, 0, 0); \
  ACC = __builtin_amdgcn_mfma_f32_16x16x32_bf16(a[RG][1], BB[1], ACC, 0, 0, 0); \
  ACC = __builtin_amdgcn_mfma_f32_16x16x32_bf16(a[RG][2], BB[2], ACC, 0, 0, 0); \
  ACC = __builtin_amdgcn_mfma_f32_16x16x32_bf16(a[RG][3], BB[3], ACC, 0, 0, 0);

#define EPI(ACC, RG, CE)                                                      \
  {                                                                           \
    float e0 = __builtin_amdgcn_exp2f(ACC[0]);                                \
    float e1 = __builtin_amdgcn_exp2f(ACC[1]);                                \
    float e2 = __builtin_amdgcn_exp2f(ACC[2]);                                \
    float e3 = __builtin_amdgcn_exp2f(ACC[3]);                                \
    rs[RG][0] += e0; rs[RG][1] += e1; rs[RG][2] += e2; rs[RG][3] += e3;       \
    CE += (e0 + e1) + (e2 + e3);                                              \
  }

#define CSTORE(CE, SUB)                                                       \
  {                                                                           \
    CE += __shfl_xor(CE, 16);                                                 \
    CE += __shfl_xor(CE, 32);                                                 \
    if (lh == 0) colred[wave][(SUB) * 16 + l15] = CE;                         \
  }

// one pipelined pair: compute subs S0,S1 from b0,b1; prefetch PF0,PF1
#define PAIR(S0, S1, PF0, PF1, DOPF)                                          \
  {                                                                           \
    f32x4 x0 = {0.f,0.f,0.f,0.f}, x1 = {0.f,0.f,0.f,0.f};                     \
    f32x4 y0 = {0.f,0.f,0.f,0.f}, y1 = {0.f,0.f,0.f,0.f};                     \
    MM4(x0, 0, b0) MM4(x1, 1, b0) MM4(y0, 0, b1) MM4(y1, 1, b1)               \
    if (DOPF) { LDB(b0, PF0) LDB(b1, PF1) }                                   \
    float ce0 = 0.f, ce1 = 0.f;                                               \
    EPI(x0, 0, ce0) EPI(x1, 1, ce0)                                           \
    EPI(y0, 0, ce1) EPI(y1, 1, ce1)                                           \
    CSTORE(ce0, S0) CSTORE(ce1, S1)                                           \
  }

__global__ __launch_bounds__(256) void sim_kernel(const __hip_bfloat16* __restrict__ znb,
                                                  float* __restrict__ rowsum,
                                                  float* __restrict__ pos, int B) {
  const ushort* zn = (const ushort*)znb;
  const int N = 2 * B;
  const int tid = threadIdx.x;
  const int wave = tid >> 6, lane = tid & 63;
  const int l15 = lane & 15, lh = lane >> 4;

  // decode upper-triangle tile (r, c), 0 <= r <= c < NS
  int rem = blockIdx.x, r = 0;
  while (rem >= (NS - r)) { rem -= (NS - r); ++r; }
  const int c = r + rem;

  const int Rr = r * S + wave * WRW;   // this wave's 32 rows
  const int Cc = c * S;                // tile's 128 cols

  __shared__ ushort lds[S * DIMD];     // 32 KB B panel
  __shared__ float colred[4][S];       // 2 KB col-sum reduce

  // ---- stage B panel (8 global_load_lds, linear dest + pre-swz source) ----
  {
    const int myCol = wave * 4 + lh;
    const int myKb = l15 ^ (myCol & 7);
    const ushort* gsrc0 = zn + (size_t)(Cc + myCol) * DIMD + myKb * 8;
    #pragma unroll
    for (int c_ = 0; c_ < 8; ++c_)
      __builtin_amdgcn_global_load_lds(
          (glb_u32*)(gsrc0 + (size_t)c_ * 16 * DIMD),
          (lds_u32*)&lds[(c_ * 16 + wave * 4) * DIMD], 16, 0, 0);
  }

  // ---- A fragments: 2 row-groups x 4 k-chunks ----
  short8 a[2][4];
  #pragma unroll
  for (int rg = 0; rg < 2; ++rg) {
    const ushort* ar = zn + (size_t)(Rr + rg * 16 + l15) * DIMD + lh * 8;
    #pragma unroll
    for (int kc = 0; kc < 4; ++kc) a[rg][kc] = *(const short8*)(ar + kc * 32);
  }

  float rs[2][4];
  #pragma unroll
  for (int rg = 0; rg < 2; ++rg)
    #pragma unroll
    for (int rr = 0; rr < 4; ++rr) rs[rg][rr] = 0.0f;

  int roff[4];
  #pragma unroll
  for (int kc = 0; kc < 4; ++kc) roff[kc] = ((kc * 4 + lh) ^ (l15 & 7)) * 8;

  __syncthreads();  // drains staging + A loads

  if (r == c) {
    // ---- diagonal tile: mask j==i, row-sums only, no mirror ----
    #pragma unroll 4
    for (int sub = 0; sub < S / 16; ++sub) {
      short8 bb[4];
      LDB(bb, sub)
      #pragma unroll
      for (int rg = 0; rg < 2; ++rg) {
        f32x4 acc = {0.f, 0.f, 0.f, 0.f};
        MM4(acc, rg, bb)
        #pragma unroll
        for (int rr = 0; rr < 4; ++rr) {
          int i_ = Rr + rg * 16 + lh * 4 + rr;   // C/D: row=(lane>>4)*4+reg
          int jg_ = Cc + sub * 16 + l15;         //       col=lane&15
          if (jg_ != i_) rs[rg][rr] += __builtin_amdgcn_exp2f(acc[rr]);
        }
      }
    }
  } else if (c == r + NPB) {
    // ---- pos tile: plain sums + positives on the local diagonal ----
    #pragma unroll 4
    for (int sub = 0; sub < S / 16; ++sub) {
      short8 bb[4];
      LDB(bb, sub)
      float ce = 0.0f;
      #pragma unroll
      for (int rg = 0; rg < 2; ++rg) {
        f32x4 acc = {0.f, 0.f, 0.f, 0.f};
        MM4(acc, rg, bb)
        #pragma unroll
        for (int rr = 0; rr < 4; ++rr) {
          int i_ = Rr + rg * 16 + lh * 4 + rr;
          int jg_ = Cc + sub * 16 + l15;
          float e = __builtin_amdgcn_exp2f(acc[rr]);
          rs[rg][rr] += e;
          ce += e;
          if (jg_ == i_ + B) {                   // local diagonal
            float s_ = acc[rr] * LN2;
            pos[i_] = s_;
            pos[i_ + B] = s_;
          }
        }
      }
      CSTORE(ce, sub)
    }
  } else {
    // ---- plain tile (1984 of 2080): hand-pipelined 2-sub loop ----
    short8 b0[4], b1[4];
    LDB(b0, 0) LDB(b1, 1)
    PAIR(0, 1, 2, 3, 1)
    PAIR(2, 3, 4, 5, 1)
    PAIR(4, 5, 6, 7, 1)
    PAIR(6, 7, 0, 0, 0)
  }

  // row-sum: reduce across the 16 lanes sharing (lane>>4), then accumulate
  #pragma unroll
  for (int rg = 0; rg < 2; ++rg) {
    #pragma unroll
    for (int rr = 0; rr < 4; ++rr) {
      #pragma unroll
      for (int off = 1; off < 16; off <<= 1)
        rs[rg][rr] += __shfl_xor(rs[rg][rr], off);
    }
  }
  if (l15 == 0) {
    #pragma unroll
    for (int rg = 0; rg < 2; ++rg)
      #pragma unroll
      for (int rr = 0; rr < 4; ++rr)
        atomicAdd(&rowsum[Rr + rg * 16 + lh * 4 + rr], rs[rg][rr]);
  }

  if (r != c) {
    // combine the 4 waves' col-sums -> mirror contribution to rowsum[j]
    __syncthreads();
    if (tid < S) {
      float cs = colred[0][tid] + colred[1][tid] + colred[2][tid] + colred[3][tid];
      atomicAdd(&rowsum[Cc + tid], cs);
    }
  }
}

// ---------------- Kernel 3: row_loss = log(sum) - pos; mean over rows -------
__global__ __launch_bounds__(256) void fin_kernel(const float* __restrict__ rowsum,
                                                  const float* __restrict__ pos,
                                                  float* __restrict__ out, int N) {
  int i = blockIdx.x * 256 + threadIdx.x;
  float li = 0.0f;
  if (i < N)
    li = __builtin_amdgcn_logf(rowsum[i]) * LN2 - pos[i];
  #pragma unroll
  for (int off = 32; off; off >>= 1) li += __shfl_xor(li, off);
  __shared__ float red[4];
  int wave = threadIdx.x >> 6, lane = threadIdx.x & 63;
  if (lane == 0) red[wave] = li;
  __syncthreads();
  if (threadIdx.x == 0) {
    float bs = red[0] + red[1] + red[2] + red[3];
    atomicAdd(out, bs / (float)N);
  }
}

extern "C" void kernel_launch(void* const* d_in, const int* in_sizes, int n_in,
                              void* d_out, int out_size, void* d_ws, size_t ws_size,
                              hipStream_t stream) {
  const float* zi = (const float*)d_in[0];
  const float* zj = (const float*)d_in[1];
  const int B = in_sizes[0] / DIMD;   // 4096
  const int N = 2 * B;                // 8192
  float* out = (float*)d_out;

  char* ws = (char*)d_ws;
  __hip_bfloat16* zn = (__hip_bfloat16*)ws;                  // 2 MB
  float* pos = (float*)(ws + (size_t)N * DIMD * 2);          // 32 KB
  float* rowsum = (float*)(ws + (size_t)N * DIMD * 2 + (size_t)N * 4);  // 32 KB

  nrm_kernel<<<N / 4, 256, 0, stream>>>(zi, zj, zn, out, rowsum, B);
  const int ntri = NS * (NS + 1) / 2;   // 2080 upper-tri tiles
  sim_kernel<<<ntri, 256, 0, stream>>>(zn, rowsum, pos, B);
  fin_kernel<<<N / 256, 256, 0, stream>>>(rowsum, pos, out, N);
}